// Round 1
// baseline (7200.715 us; speedup 1.0000x reference)
//
#include <hip/hip_runtime.h>

#define THREADS 256

// ---------------------------------------------------------------------------
// Edge-index dtype detection: if the buffer is little-endian int64 with values
// < 2^31, every odd 32-bit word is zero. Random int32 node ids make that
// astronomically unlikely. flag=1 -> int64 layout, flag=0 -> int32 layout.
// ---------------------------------------------------------------------------
__global__ __launch_bounds__(64)
void detect_kernel(const unsigned* __restrict__ ei_words, int* __restrict__ flag) {
    if (threadIdx.x == 0 && blockIdx.x == 0) {
        int allzero = 1;
        for (int i = 0; i < 64; ++i) {
            if (ei_words[2 * i + 1] != 0u) { allzero = 0; break; }
        }
        *flag = allzero;
    }
}

// Decode edge index into int32 src/dst and accumulate in-degree counts.
__global__ __launch_bounds__(THREADS)
void decode_count_kernel(const void* __restrict__ ei, const int* __restrict__ flag,
                         int* __restrict__ src, int* __restrict__ dst,
                         float* __restrict__ cnt, int E) {
    int i = blockIdx.x * THREADS + threadIdx.x;
    if (i >= E) return;
    int s, t;
    if (*flag) {
        const long long* p = (const long long*)ei;
        s = (int)p[i];
        t = (int)p[E + i];
    } else {
        const int* p = (const int*)ei;
        s = p[i];
        t = p[E + i];
    }
    src[i] = s;
    dst[i] = t;
    atomicAdd(&cnt[t], 1.0f);
}

// ---------------------------------------------------------------------------
// Scatter-add: agg[dst] += h[src], one float4 chunk per thread.
// Consecutive threads share an edge (chunk index varies fastest) so the edge
// id load broadcasts and the feature reads/atomics are contiguous per group.
// ---------------------------------------------------------------------------
template <int D>
__global__ __launch_bounds__(THREADS)
void scatter_kernel(const int* __restrict__ src, const int* __restrict__ dst,
                    const float* __restrict__ h, float* __restrict__ agg,
                    long long total) {
    constexpr int CH = D / 4;  // float4 chunks per row (power of 2)
    long long idx = (long long)blockIdx.x * THREADS + threadIdx.x;
    if (idx >= total) return;
    int e = (int)(idx / CH);
    int c = (int)(idx & (CH - 1));
    int s = src[e];
    int t = dst[e];
    const float4 v = *(const float4*)(h + (size_t)s * D + 4 * c);
    float* p = agg + (size_t)t * D + 4 * c;
    atomicAdd(p + 0, v.x);
    atomicAdd(p + 1, v.y);
    atomicAdd(p + 2, v.z);
    atomicAdd(p + 3, v.w);
}

// ---------------------------------------------------------------------------
// Fused layer: hout = tanh((agg/max(cnt,1)) @ Wl + hin @ Wr + b)
// Both weight matrices staged in LDS (<= 64 KB total). Each thread owns one
// row and 4 output columns; row-value loads broadcast within the wave.
// ---------------------------------------------------------------------------
template <int D_IN, int D_OUT>
__global__ __launch_bounds__(THREADS)
void layer_kernel(const float* __restrict__ agg, const float* __restrict__ cnt,
                  const float* __restrict__ hin,
                  const float* __restrict__ Wl, const float* __restrict__ Wr,
                  const float* __restrict__ bias,
                  float* __restrict__ hout, int n) {
    constexpr int TPR = D_OUT / 4;     // threads per row
    constexpr int RPB = THREADS / TPR; // rows per block
    __shared__ float sWl[D_IN * D_OUT];
    __shared__ float sWr[D_IN * D_OUT];
    __shared__ float sb[D_OUT];
    for (int i = threadIdx.x; i < D_IN * D_OUT; i += THREADS) {
        sWl[i] = Wl[i];
        sWr[i] = Wr[i];
    }
    if (threadIdx.x < D_OUT) sb[threadIdx.x] = bias[threadIdx.x];
    __syncthreads();

    const int cg   = threadIdx.x % TPR;
    const int rsub = threadIdx.x / TPR;
    const int row  = blockIdx.x * RPB + rsub;
    if (row >= n) return;

    const float inv = 1.0f / fmaxf(cnt[row], 1.0f);
    const float* __restrict__ ar = agg + (size_t)row * D_IN;
    const float* __restrict__ hr = hin + (size_t)row * D_IN;

    float a0 = 0.f, a1 = 0.f, a2 = 0.f, a3 = 0.f;
#pragma unroll 8
    for (int k = 0; k < D_IN; ++k) {
        const float am = ar[k] * inv;
        const float ah = hr[k];
        const float4 wl = *(const float4*)(sWl + k * D_OUT + 4 * cg);
        const float4 wr = *(const float4*)(sWr + k * D_OUT + 4 * cg);
        a0 += am * wl.x + ah * wr.x;
        a1 += am * wl.y + ah * wr.y;
        a2 += am * wl.z + ah * wr.z;
        a3 += am * wl.w + ah * wr.w;
    }
    float4 o;
    o.x = tanhf(a0 + sb[4 * cg + 0]);
    o.y = tanhf(a1 + sb[4 * cg + 1]);
    o.z = tanhf(a2 + sb[4 * cg + 2]);
    o.w = tanhf(a3 + sb[4 * cg + 3]);
    *(float4*)(hout + (size_t)row * D_OUT + 4 * cg) = o;
}

// ---------------------------------------------------------------------------
// Head: out = h @ Wlin + blin   ([n,64] x [64,10])
// ---------------------------------------------------------------------------
__global__ __launch_bounds__(THREADS)
void head_kernel(const float* __restrict__ h, const float* __restrict__ W,
                 const float* __restrict__ bias, float* __restrict__ out, int n) {
    __shared__ float sW[64 * 10];
    __shared__ float sb[10];
    for (int i = threadIdx.x; i < 640; i += THREADS) sW[i] = W[i];
    if (threadIdx.x < 10) sb[threadIdx.x] = bias[threadIdx.x];
    __syncthreads();
    int idx = blockIdx.x * THREADS + threadIdx.x;
    if (idx >= n * 10) return;
    int row = idx / 10;
    int col = idx - row * 10;
    const float* __restrict__ hr = h + (size_t)row * 64;
    float acc = sb[col];
#pragma unroll 16
    for (int k = 0; k < 64; ++k) acc += hr[k] * sW[k * 10 + col];
    out[idx] = acc;
}

extern "C" void kernel_launch(void* const* d_in, const int* in_sizes, int n_in,
                              void* d_out, int out_size, void* d_ws, size_t ws_size,
                              hipStream_t stream) {
    const float* x    = (const float*)d_in[0];
    const void*  ei   = d_in[1];
    const float* W1l  = (const float*)d_in[2];
    const float* W1r  = (const float*)d_in[3];
    const float* b1   = (const float*)d_in[4];
    const float* W2l  = (const float*)d_in[5];
    const float* W2r  = (const float*)d_in[6];
    const float* b2   = (const float*)d_in[7];
    const float* W3l  = (const float*)d_in[8];
    const float* W3r  = (const float*)d_in[9];
    const float* b3   = (const float*)d_in[10];
    const float* Wlin = (const float*)d_in[11];
    const float* blin = (const float*)d_in[12];
    float* out = (float*)d_out;

    const int n = in_sizes[0] / 128;   // 100000
    const int E = in_sizes[1] / 2;     // 1600000

    // --- workspace carve-up (all offsets 256B aligned) ---
    char* ws = (char*)d_ws;
    size_t off = 0;
    auto carve = [&](size_t bytes) {
        void* p = ws + off;
        off += (bytes + 255) & ~(size_t)255;
        return p;
    };
    int*   flag = (int*)  carve(256);
    float* cnt  = (float*)carve((size_t)n * 4);
    int*   src  = (int*)  carve((size_t)E * 4);
    int*   dst  = (int*)  carve((size_t)E * 4);
    float* agg  = (float*)carve((size_t)n * 128 * 4);
    float* h1   = (float*)carve((size_t)n * 64 * 4);
    float* h2   = (float*)carve((size_t)n * 128 * 4);
    float* h3   = h1;  // h1 dead after layer 2's GEMM; reuse for h3
    (void)ws_size;

    // --- edge decode + degree count (once; same graph for all layers) ---
    detect_kernel<<<1, 64, 0, stream>>>((const unsigned*)ei, flag);
    hipMemsetAsync(cnt, 0, (size_t)n * 4, stream);
    decode_count_kernel<<<(E + THREADS - 1) / THREADS, THREADS, 0, stream>>>(
        ei, flag, src, dst, cnt, E);

    // --- layer 1: d_in=128 -> d_out=64 ---
    hipMemsetAsync(agg, 0, (size_t)n * 128 * 4, stream);
    {
        long long total = (long long)E * 32;
        scatter_kernel<128><<<(int)((total + THREADS - 1) / THREADS), THREADS, 0, stream>>>(
            src, dst, x, agg, total);
    }
    layer_kernel<128, 64><<<(n + 15) / 16, THREADS, 0, stream>>>(
        agg, cnt, x, W1l, W1r, b1, h1, n);

    // --- layer 2: 64 -> 128 ---
    hipMemsetAsync(agg, 0, (size_t)n * 64 * 4, stream);
    {
        long long total = (long long)E * 16;
        scatter_kernel<64><<<(int)((total + THREADS - 1) / THREADS), THREADS, 0, stream>>>(
            src, dst, h1, agg, total);
    }
    layer_kernel<64, 128><<<(n + 7) / 8, THREADS, 0, stream>>>(
        agg, cnt, h1, W2l, W2r, b2, h2, n);

    // --- layer 3: 128 -> 64 ---
    hipMemsetAsync(agg, 0, (size_t)n * 128 * 4, stream);
    {
        long long total = (long long)E * 32;
        scatter_kernel<128><<<(int)((total + THREADS - 1) / THREADS), THREADS, 0, stream>>>(
            src, dst, h2, agg, total);
    }
    layer_kernel<128, 64><<<(n + 15) / 16, THREADS, 0, stream>>>(
        agg, cnt, h2, W3l, W3r, b3, h3, n);

    // --- head: [n,64] @ [64,10] + b ---
    head_kernel<<<(n * 10 + THREADS - 1) / THREADS, THREADS, 0, stream>>>(
        h3, Wlin, blin, out, n);
}

// Round 2
// 930.749 us; speedup vs baseline: 7.7365x; 7.7365x over previous
//
#include <hip/hip_runtime.h>

#define THREADS 256

// ---------------------------------------------------------------------------
// Edge-index dtype detection: little-endian int64 values < 2^31 have all-zero
// odd 32-bit words. flag=1 -> int64 layout, flag=0 -> int32 layout.
// ---------------------------------------------------------------------------
__global__ __launch_bounds__(64)
void detect_kernel(const unsigned* __restrict__ ei_words, int* __restrict__ flag) {
    if (threadIdx.x == 0 && blockIdx.x == 0) {
        int allzero = 1;
        for (int i = 0; i < 64; ++i) {
            if (ei_words[2 * i + 1] != 0u) { allzero = 0; break; }
        }
        *flag = allzero;
    }
}

__device__ __forceinline__ void load_edge(const void* ei, int is64, int E, int i,
                                          int& s, int& t) {
    if (is64) {
        const long long* p = (const long long*)ei;
        s = (int)p[i];
        t = (int)p[E + i];
    } else {
        const int* p = (const int*)ei;
        s = p[i];
        t = p[E + i];
    }
}

// In-degree histogram (int atomics, 1.6M total).
__global__ __launch_bounds__(THREADS)
void count_kernel(const void* __restrict__ ei, const int* __restrict__ flag,
                  int* __restrict__ cnt, int E) {
    int i = blockIdx.x * THREADS + threadIdx.x;
    if (i >= E) return;
    int s, t;
    load_edge(ei, *flag, E, i, s, t);
    (void)s;
    atomicAdd(&cnt[t], 1);
}

// ---------------------------------------------------------------------------
// Single-block exclusive prefix sum over n counts -> rowptr[n+1] and a second
// copy wptr[n] (consumed by the placement pass). Wave-shuffle scan, 3 syncs
// per 1024-element chunk.
// ---------------------------------------------------------------------------
__global__ __launch_bounds__(1024)
void scan_kernel(const int* __restrict__ cnt, int* __restrict__ rowptr,
                 int* __restrict__ wptr, int n) {
    __shared__ int wsum[16];
    const int lane = threadIdx.x & 63;
    const int wid  = threadIdx.x >> 6;
    int run = 0;
    for (int base = 0; base < n; base += 1024) {
        const int i = base + (int)threadIdx.x;
        const int v = (i < n) ? cnt[i] : 0;
        // wave-inclusive scan
        int incl = v;
#pragma unroll
        for (int off = 1; off < 64; off <<= 1) {
            int t = __shfl_up(incl, off, 64);
            if (lane >= off) incl += t;
        }
        if (lane == 63) wsum[wid] = incl;
        __syncthreads();
        if (wid == 0) {
            int wv = (lane < 16) ? wsum[lane] : 0;
#pragma unroll
            for (int off = 1; off < 16; off <<= 1) {
                int t = __shfl_up(wv, off, 64);
                if (lane >= off) wv += t;
            }
            if (lane < 16) wsum[lane] = wv;
        }
        __syncthreads();
        const int wbase = (wid > 0) ? wsum[wid - 1] : 0;
        const int total = wsum[15];
        incl += wbase;
        const int excl = incl - v;
        if (i < n) {
            rowptr[i] = run + excl;
            wptr[i]   = run + excl;
        }
        run += total;
        __syncthreads();  // protect wsum before next chunk overwrites
    }
    if (threadIdx.x == 0) rowptr[n] = run;
}

// Counting-sort placement: esrc[] = edge sources grouped by destination.
__global__ __launch_bounds__(THREADS)
void place_kernel(const void* __restrict__ ei, const int* __restrict__ flag,
                  int* __restrict__ wptr, int* __restrict__ esrc, int E) {
    int i = blockIdx.x * THREADS + threadIdx.x;
    if (i >= E) return;
    int s, t;
    load_edge(ei, *flag, E, i, s, t);
    int p = atomicAdd(&wptr[t], 1);
    esrc[p] = s;
}

// ---------------------------------------------------------------------------
// Gather-mean: agg[v] = mean_{e: dst(e)=v} h[src(e)].  D/4 threads per node,
// each owns one float4 column chunk; a node's edge list is walked serially,
// rows read 512B-coalesced across the chunk group. No atomics.
// ---------------------------------------------------------------------------
template <int D>
__global__ __launch_bounds__(THREADS)
void gather_kernel(const int* __restrict__ rowptr, const int* __restrict__ esrc,
                   const float* __restrict__ h, float* __restrict__ agg, int n) {
    constexpr int CH  = D / 4;        // float4 chunks per row
    constexpr int NPB = THREADS / CH; // nodes per block
    const int node = blockIdx.x * NPB + (int)(threadIdx.x / CH);
    const int c    = threadIdx.x & (CH - 1);
    if (node >= n) return;
    const int begin = rowptr[node];
    const int end   = rowptr[node + 1];
    float4 acc = make_float4(0.f, 0.f, 0.f, 0.f);
    for (int e = begin; e < end; ++e) {
        const int s = esrc[e];
        const float4 v = *(const float4*)(h + (size_t)s * D + 4 * c);
        acc.x += v.x; acc.y += v.y; acc.z += v.z; acc.w += v.w;
    }
    const float inv = 1.0f / fmaxf((float)(end - begin), 1.0f);
    float4 o = make_float4(acc.x * inv, acc.y * inv, acc.z * inv, acc.w * inv);
    *(float4*)(agg + (size_t)node * D + 4 * c) = o;
}

// ---------------------------------------------------------------------------
// Fused layer: hout = tanh(agg @ Wl + hin @ Wr + b)   (agg already the mean)
// ---------------------------------------------------------------------------
template <int D_IN, int D_OUT>
__global__ __launch_bounds__(THREADS)
void layer_kernel(const float* __restrict__ agg, const float* __restrict__ hin,
                  const float* __restrict__ Wl, const float* __restrict__ Wr,
                  const float* __restrict__ bias,
                  float* __restrict__ hout, int n) {
    constexpr int TPR = D_OUT / 4;     // threads per row
    constexpr int RPB = THREADS / TPR; // rows per block
    __shared__ float sWl[D_IN * D_OUT];
    __shared__ float sWr[D_IN * D_OUT];
    __shared__ float sb[D_OUT];
    for (int i = threadIdx.x; i < D_IN * D_OUT; i += THREADS) {
        sWl[i] = Wl[i];
        sWr[i] = Wr[i];
    }
    if (threadIdx.x < D_OUT) sb[threadIdx.x] = bias[threadIdx.x];
    __syncthreads();

    const int cg   = threadIdx.x % TPR;
    const int rsub = threadIdx.x / TPR;
    const int row  = blockIdx.x * RPB + rsub;
    if (row >= n) return;

    const float* __restrict__ ar = agg + (size_t)row * D_IN;
    const float* __restrict__ hr = hin + (size_t)row * D_IN;

    float a0 = 0.f, a1 = 0.f, a2 = 0.f, a3 = 0.f;
#pragma unroll 8
    for (int k = 0; k < D_IN; ++k) {
        const float am = ar[k];
        const float ah = hr[k];
        const float4 wl = *(const float4*)(sWl + k * D_OUT + 4 * cg);
        const float4 wr = *(const float4*)(sWr + k * D_OUT + 4 * cg);
        a0 += am * wl.x + ah * wr.x;
        a1 += am * wl.y + ah * wr.y;
        a2 += am * wl.z + ah * wr.z;
        a3 += am * wl.w + ah * wr.w;
    }
    float4 o;
    o.x = tanhf(a0 + sb[4 * cg + 0]);
    o.y = tanhf(a1 + sb[4 * cg + 1]);
    o.z = tanhf(a2 + sb[4 * cg + 2]);
    o.w = tanhf(a3 + sb[4 * cg + 3]);
    *(float4*)(hout + (size_t)row * D_OUT + 4 * cg) = o;
}

// ---------------------------------------------------------------------------
// Head: out = h @ Wlin + blin   ([n,64] x [64,10])
// ---------------------------------------------------------------------------
__global__ __launch_bounds__(THREADS)
void head_kernel(const float* __restrict__ h, const float* __restrict__ W,
                 const float* __restrict__ bias, float* __restrict__ out, int n) {
    __shared__ float sW[64 * 10];
    __shared__ float sb[10];
    for (int i = threadIdx.x; i < 640; i += THREADS) sW[i] = W[i];
    if (threadIdx.x < 10) sb[threadIdx.x] = bias[threadIdx.x];
    __syncthreads();
    int idx = blockIdx.x * THREADS + threadIdx.x;
    if (idx >= n * 10) return;
    int row = idx / 10;
    int col = idx - row * 10;
    const float* __restrict__ hr = h + (size_t)row * 64;
    float acc = sb[col];
#pragma unroll 16
    for (int k = 0; k < 64; ++k) acc += hr[k] * sW[k * 10 + col];
    out[idx] = acc;
}

extern "C" void kernel_launch(void* const* d_in, const int* in_sizes, int n_in,
                              void* d_out, int out_size, void* d_ws, size_t ws_size,
                              hipStream_t stream) {
    const float* x    = (const float*)d_in[0];
    const void*  ei   = d_in[1];
    const float* W1l  = (const float*)d_in[2];
    const float* W1r  = (const float*)d_in[3];
    const float* b1   = (const float*)d_in[4];
    const float* W2l  = (const float*)d_in[5];
    const float* W2r  = (const float*)d_in[6];
    const float* b2   = (const float*)d_in[7];
    const float* W3l  = (const float*)d_in[8];
    const float* W3r  = (const float*)d_in[9];
    const float* b3   = (const float*)d_in[10];
    const float* Wlin = (const float*)d_in[11];
    const float* blin = (const float*)d_in[12];
    float* out = (float*)d_out;

    const int n = in_sizes[0] / 128;   // 100000
    const int E = in_sizes[1] / 2;     // 1600000

    // --- workspace carve-up (~136 MB total) ---
    char* ws = (char*)d_ws;
    size_t off = 0;
    auto carve = [&](size_t bytes) {
        void* p = ws + off;
        off += (bytes + 255) & ~(size_t)255;
        return p;
    };
    int*   flag   = (int*)  carve(256);
    int*   cnt    = (int*)  carve((size_t)n * 4);
    int*   rowptr = (int*)  carve((size_t)(n + 1) * 4);
    int*   wptr   = (int*)  carve((size_t)n * 4);
    int*   esrc   = (int*)  carve((size_t)E * 4);
    float* agg    = (float*)carve((size_t)n * 128 * 4);
    float* h1     = (float*)carve((size_t)n * 64 * 4);
    float* h2     = (float*)carve((size_t)n * 128 * 4);
    float* h3     = h1;  // h1 dead after layer 2; reuse
    (void)ws_size;

    const int eblocks = (E + THREADS - 1) / THREADS;

    // --- CSR build (once; graph shared by all layers) ---
    detect_kernel<<<1, 64, 0, stream>>>((const unsigned*)ei, flag);
    hipMemsetAsync(cnt, 0, (size_t)n * 4, stream);
    count_kernel<<<eblocks, THREADS, 0, stream>>>(ei, flag, cnt, E);
    scan_kernel<<<1, 1024, 0, stream>>>(cnt, rowptr, wptr, n);
    place_kernel<<<eblocks, THREADS, 0, stream>>>(ei, flag, wptr, esrc, E);

    // --- layer 1: 128 -> 64 ---
    gather_kernel<128><<<(n * 32 + THREADS - 1) / THREADS, THREADS, 0, stream>>>(
        rowptr, esrc, x, agg, n);
    layer_kernel<128, 64><<<(n + 15) / 16, THREADS, 0, stream>>>(
        agg, x, W1l, W1r, b1, h1, n);

    // --- layer 2: 64 -> 128 ---
    gather_kernel<64><<<(n * 16 + THREADS - 1) / THREADS, THREADS, 0, stream>>>(
        rowptr, esrc, h1, agg, n);
    layer_kernel<64, 128><<<(n + 7) / 8, THREADS, 0, stream>>>(
        agg, h1, W2l, W2r, b2, h2, n);

    // --- layer 3: 128 -> 64 ---
    gather_kernel<128><<<(n * 32 + THREADS - 1) / THREADS, THREADS, 0, stream>>>(
        rowptr, esrc, h2, agg, n);
    layer_kernel<128, 64><<<(n + 15) / 16, THREADS, 0, stream>>>(
        agg, h2, W3l, W3r, b3, h3, n);

    // --- head ---
    head_kernel<<<(n * 10 + THREADS - 1) / THREADS, THREADS, 0, stream>>>(
        h3, Wlin, blin, out, n);
}

// Round 3
// 606.244 us; speedup vs baseline: 11.8776x; 1.5353x over previous
//
#include <hip/hip_runtime.h>

#define THREADS 256

// ---------------------------------------------------------------------------
// Edge-index dtype detection: little-endian int64 values < 2^31 have all-zero
// odd 32-bit words. flag=1 -> int64 layout, flag=0 -> int32 layout.
// ---------------------------------------------------------------------------
__global__ __launch_bounds__(64)
void detect_kernel(const unsigned* __restrict__ ei_words, int* __restrict__ flag) {
    if (threadIdx.x == 0 && blockIdx.x == 0) {
        int allzero = 1;
        for (int i = 0; i < 64; ++i) {
            if (ei_words[2 * i + 1] != 0u) { allzero = 0; break; }
        }
        *flag = allzero;
    }
}

__device__ __forceinline__ void load_edge(const void* ei, int is64, int E, int i,
                                          int& s, int& t) {
    if (is64) {
        const long long* p = (const long long*)ei;
        s = (int)p[i];
        t = (int)p[E + i];
    } else {
        const int* p = (const int*)ei;
        s = p[i];
        t = p[E + i];
    }
}

// In-degree histogram (int atomics, 1.6M total).
__global__ __launch_bounds__(THREADS)
void count_kernel(const void* __restrict__ ei, const int* __restrict__ flag,
                  int* __restrict__ cnt, int E) {
    int i = blockIdx.x * THREADS + threadIdx.x;
    if (i >= E) return;
    int s, t;
    load_edge(ei, *flag, E, i, s, t);
    (void)s;
    atomicAdd(&cnt[t], 1);
}

// ---------------------------------------------------------------------------
// Three-kernel exclusive scan of cnt[n] -> rowptr[n+1], wptr[n].
// Chunk = 1024 elements per block.
// ---------------------------------------------------------------------------
__global__ __launch_bounds__(256)
void scan_partial_kernel(const int* __restrict__ cnt, int* __restrict__ bsum, int n) {
    const int base = blockIdx.x * 1024;
    int v = 0;
    for (int i = threadIdx.x; i < 1024; i += 256) {
        const int idx = base + i;
        v += (idx < n) ? cnt[idx] : 0;
    }
#pragma unroll
    for (int off = 32; off > 0; off >>= 1) v += __shfl_down(v, off, 64);
    __shared__ int ws[4];
    if ((threadIdx.x & 63) == 0) ws[threadIdx.x >> 6] = v;
    __syncthreads();
    if (threadIdx.x == 0) bsum[blockIdx.x] = ws[0] + ws[1] + ws[2] + ws[3];
}

__global__ __launch_bounds__(64)
void scan_bsum_kernel(int* __restrict__ bsum, int* __restrict__ total, int nb) {
    if (threadIdx.x == 0) {
        int run = 0;
        for (int i = 0; i < nb; ++i) { int t = bsum[i]; bsum[i] = run; run += t; }
        *total = run;  // becomes rowptr[n]
    }
}

__global__ __launch_bounds__(256)
void scan_final_kernel(const int* __restrict__ cnt, const int* __restrict__ bsum,
                       int* __restrict__ rowptr, int* __restrict__ wptr, int n) {
    const int base = blockIdx.x * 1024 + threadIdx.x * 4;
    int a0 = 0, a1 = 0, a2 = 0, a3 = 0;
    if (base + 3 < n) {
        a0 = cnt[base]; a1 = cnt[base + 1]; a2 = cnt[base + 2]; a3 = cnt[base + 3];
    } else {
        if (base + 0 < n) a0 = cnt[base + 0];
        if (base + 1 < n) a1 = cnt[base + 1];
        if (base + 2 < n) a2 = cnt[base + 2];
        if (base + 3 < n) a3 = cnt[base + 3];
    }
    const int mysum = a0 + a1 + a2 + a3;
    const int lane = threadIdx.x & 63;
    const int wid  = threadIdx.x >> 6;
    int incl = mysum;
#pragma unroll
    for (int off = 1; off < 64; off <<= 1) {
        int t = __shfl_up(incl, off, 64);
        if (lane >= off) incl += t;
    }
    __shared__ int ws[4];
    if (lane == 63) ws[wid] = incl;
    __syncthreads();
    int woff = 0;
    for (int w = 0; w < wid; ++w) woff += ws[w];
    int pre = bsum[blockIdx.x] + woff + (incl - mysum);
    if (base + 0 < n) { rowptr[base + 0] = pre; wptr[base + 0] = pre; } pre += a0;
    if (base + 1 < n) { rowptr[base + 1] = pre; wptr[base + 1] = pre; } pre += a1;
    if (base + 2 < n) { rowptr[base + 2] = pre; wptr[base + 2] = pre; } pre += a2;
    if (base + 3 < n) { rowptr[base + 3] = pre; wptr[base + 3] = pre; }
}

// Counting-sort placement: esrc[] = edge sources grouped by destination.
__global__ __launch_bounds__(THREADS)
void place_kernel(const void* __restrict__ ei, const int* __restrict__ flag,
                  int* __restrict__ wptr, int* __restrict__ esrc, int E) {
    int i = blockIdx.x * THREADS + threadIdx.x;
    if (i >= E) return;
    int s, t;
    load_edge(ei, *flag, E, i, s, t);
    int p = atomicAdd(&wptr[t], 1);
    esrc[p] = s;
}

// ---------------------------------------------------------------------------
// Dual GEMM: p = x @ Wl, q = x @ Wr.  [n, D_IN] x [D_IN, D_OUT] twice.
// 512 threads; each thread: R rows x 4 cols for both outputs. Weights in LDS
// (one read serves R rows).
// ---------------------------------------------------------------------------
template <int D_IN, int D_OUT, int R>
__global__ __launch_bounds__(512)
void dual_gemm_kernel(const float* __restrict__ x,
                      const float* __restrict__ Wl, const float* __restrict__ Wr,
                      float* __restrict__ p, float* __restrict__ q, int n) {
    constexpr int TPR = D_OUT / 4;
    constexpr int RPB = (512 / TPR) * R;
    __shared__ float sWl[D_IN * D_OUT];
    __shared__ float sWr[D_IN * D_OUT];
    for (int i = threadIdx.x; i < D_IN * D_OUT / 4; i += 512) {
        ((float4*)sWl)[i] = ((const float4*)Wl)[i];
        ((float4*)sWr)[i] = ((const float4*)Wr)[i];
    }
    __syncthreads();
    const int cg   = threadIdx.x % TPR;
    const int rs   = threadIdx.x / TPR;
    const int row0 = blockIdx.x * RPB + rs * R;
    float4 aL[R], aR[R];
#pragma unroll
    for (int r = 0; r < R; ++r) {
        aL[r] = make_float4(0.f, 0.f, 0.f, 0.f);
        aR[r] = make_float4(0.f, 0.f, 0.f, 0.f);
    }
#pragma unroll 4
    for (int k4 = 0; k4 < D_IN / 4; ++k4) {
        float4 xv[R];
#pragma unroll
        for (int r = 0; r < R; ++r) {
            const int row = min(row0 + r, n - 1);
            xv[r] = *(const float4*)(x + (size_t)row * D_IN + 4 * k4);
        }
#pragma unroll
        for (int j = 0; j < 4; ++j) {
            const float4 wl = *(const float4*)(sWl + (4 * k4 + j) * D_OUT + 4 * cg);
            const float4 wr = *(const float4*)(sWr + (4 * k4 + j) * D_OUT + 4 * cg);
#pragma unroll
            for (int r = 0; r < R; ++r) {
                const float a = ((const float*)&xv[r])[j];
                aL[r].x += a * wl.x; aL[r].y += a * wl.y;
                aL[r].z += a * wl.z; aL[r].w += a * wl.w;
                aR[r].x += a * wr.x; aR[r].y += a * wr.y;
                aR[r].z += a * wr.z; aR[r].w += a * wr.w;
            }
        }
    }
#pragma unroll
    for (int r = 0; r < R; ++r) {
        const int row = row0 + r;
        if (row < n) {
            *(float4*)(p + (size_t)row * D_OUT + 4 * cg) = aL[r];
            *(float4*)(q + (size_t)row * D_OUT + 4 * cg) = aR[r];
        }
    }
}

// ---------------------------------------------------------------------------
// Gather-mean + residual + bias + tanh:  h[v] = tanh(mean_e p[src(e)] + q[v] + b)
// D=64: 16 threads per node, 4 edges unrolled (independent load chains).
// ---------------------------------------------------------------------------
__global__ __launch_bounds__(THREADS)
void gather_fuse_kernel(const int* __restrict__ rowptr, const int* __restrict__ esrc,
                        const float* __restrict__ p, const float* __restrict__ q,
                        const float* __restrict__ bias, float* __restrict__ h, int n) {
    constexpr int CH  = 16;             // 64/4
    constexpr int NPB = THREADS / CH;
    const int node = blockIdx.x * NPB + (int)(threadIdx.x / CH);
    const int c    = threadIdx.x & (CH - 1);
    if (node >= n) return;
    const int begin = rowptr[node];
    const int end   = rowptr[node + 1];
    float4 acc = make_float4(0.f, 0.f, 0.f, 0.f);
    int e = begin;
    for (; e + 4 <= end; e += 4) {
        const int s0 = esrc[e + 0], s1 = esrc[e + 1], s2 = esrc[e + 2], s3 = esrc[e + 3];
        const float4 v0 = *(const float4*)(p + (size_t)s0 * 64 + 4 * c);
        const float4 v1 = *(const float4*)(p + (size_t)s1 * 64 + 4 * c);
        const float4 v2 = *(const float4*)(p + (size_t)s2 * 64 + 4 * c);
        const float4 v3 = *(const float4*)(p + (size_t)s3 * 64 + 4 * c);
        acc.x += v0.x + v1.x + v2.x + v3.x;
        acc.y += v0.y + v1.y + v2.y + v3.y;
        acc.z += v0.z + v1.z + v2.z + v3.z;
        acc.w += v0.w + v1.w + v2.w + v3.w;
    }
    for (; e < end; ++e) {
        const int s = esrc[e];
        const float4 v = *(const float4*)(p + (size_t)s * 64 + 4 * c);
        acc.x += v.x; acc.y += v.y; acc.z += v.z; acc.w += v.w;
    }
    const float inv = 1.0f / fmaxf((float)(end - begin), 1.0f);
    const float4 qv = *(const float4*)(q + (size_t)node * 64 + 4 * c);
    const float4 bv = *(const float4*)(bias + 4 * c);
    float4 o;
    o.x = tanhf(acc.x * inv + qv.x + bv.x);
    o.y = tanhf(acc.y * inv + qv.y + bv.y);
    o.z = tanhf(acc.z * inv + qv.z + bv.z);
    o.w = tanhf(acc.w * inv + qv.w + bv.w);
    *(float4*)(h + (size_t)node * 64 + 4 * c) = o;
}

// Plain gather-mean (layer 2): agg[v] = mean_e h[src(e)], D=64.
__global__ __launch_bounds__(THREADS)
void gather_mean_kernel(const int* __restrict__ rowptr, const int* __restrict__ esrc,
                        const float* __restrict__ h, float* __restrict__ agg, int n) {
    constexpr int CH  = 16;
    constexpr int NPB = THREADS / CH;
    const int node = blockIdx.x * NPB + (int)(threadIdx.x / CH);
    const int c    = threadIdx.x & (CH - 1);
    if (node >= n) return;
    const int begin = rowptr[node];
    const int end   = rowptr[node + 1];
    float4 acc = make_float4(0.f, 0.f, 0.f, 0.f);
    int e = begin;
    for (; e + 4 <= end; e += 4) {
        const int s0 = esrc[e + 0], s1 = esrc[e + 1], s2 = esrc[e + 2], s3 = esrc[e + 3];
        const float4 v0 = *(const float4*)(h + (size_t)s0 * 64 + 4 * c);
        const float4 v1 = *(const float4*)(h + (size_t)s1 * 64 + 4 * c);
        const float4 v2 = *(const float4*)(h + (size_t)s2 * 64 + 4 * c);
        const float4 v3 = *(const float4*)(h + (size_t)s3 * 64 + 4 * c);
        acc.x += v0.x + v1.x + v2.x + v3.x;
        acc.y += v0.y + v1.y + v2.y + v3.y;
        acc.z += v0.z + v1.z + v2.z + v3.z;
        acc.w += v0.w + v1.w + v2.w + v3.w;
    }
    for (; e < end; ++e) {
        const int s = esrc[e];
        const float4 v = *(const float4*)(h + (size_t)s * 64 + 4 * c);
        acc.x += v.x; acc.y += v.y; acc.z += v.z; acc.w += v.w;
    }
    const float inv = 1.0f / fmaxf((float)(end - begin), 1.0f);
    float4 o = make_float4(acc.x * inv, acc.y * inv, acc.z * inv, acc.w * inv);
    *(float4*)(agg + (size_t)node * 64 + 4 * c) = o;
}

// ---------------------------------------------------------------------------
// Fused layer (layer 2): hout = tanh(agg @ Wl + hin @ Wr + b), 64 -> 128.
// Same R-rows-per-thread structure as dual_gemm.
// ---------------------------------------------------------------------------
template <int D_IN, int D_OUT, int R>
__global__ __launch_bounds__(512)
void layer_kernel(const float* __restrict__ agg, const float* __restrict__ hin,
                  const float* __restrict__ Wl, const float* __restrict__ Wr,
                  const float* __restrict__ bias,
                  float* __restrict__ hout, int n) {
    constexpr int TPR = D_OUT / 4;
    constexpr int RPB = (512 / TPR) * R;
    __shared__ float sWl[D_IN * D_OUT];
    __shared__ float sWr[D_IN * D_OUT];
    __shared__ float sb[D_OUT];
    for (int i = threadIdx.x; i < D_IN * D_OUT / 4; i += 512) {
        ((float4*)sWl)[i] = ((const float4*)Wl)[i];
        ((float4*)sWr)[i] = ((const float4*)Wr)[i];
    }
    if (threadIdx.x < D_OUT) sb[threadIdx.x] = bias[threadIdx.x];
    __syncthreads();
    const int cg   = threadIdx.x % TPR;
    const int rs   = threadIdx.x / TPR;
    const int row0 = blockIdx.x * RPB + rs * R;
    float4 acc[R];
#pragma unroll
    for (int r = 0; r < R; ++r) acc[r] = make_float4(0.f, 0.f, 0.f, 0.f);
#pragma unroll 4
    for (int k4 = 0; k4 < D_IN / 4; ++k4) {
        float4 av[R], hv[R];
#pragma unroll
        for (int r = 0; r < R; ++r) {
            const int row = min(row0 + r, n - 1);
            av[r] = *(const float4*)(agg + (size_t)row * D_IN + 4 * k4);
            hv[r] = *(const float4*)(hin + (size_t)row * D_IN + 4 * k4);
        }
#pragma unroll
        for (int j = 0; j < 4; ++j) {
            const float4 wl = *(const float4*)(sWl + (4 * k4 + j) * D_OUT + 4 * cg);
            const float4 wr = *(const float4*)(sWr + (4 * k4 + j) * D_OUT + 4 * cg);
#pragma unroll
            for (int r = 0; r < R; ++r) {
                const float a = ((const float*)&av[r])[j];
                const float b = ((const float*)&hv[r])[j];
                acc[r].x += a * wl.x + b * wr.x;
                acc[r].y += a * wl.y + b * wr.y;
                acc[r].z += a * wl.z + b * wr.z;
                acc[r].w += a * wl.w + b * wr.w;
            }
        }
    }
#pragma unroll
    for (int r = 0; r < R; ++r) {
        const int row = row0 + r;
        if (row < n) {
            float4 o;
            o.x = tanhf(acc[r].x + sb[4 * cg + 0]);
            o.y = tanhf(acc[r].y + sb[4 * cg + 1]);
            o.z = tanhf(acc[r].z + sb[4 * cg + 2]);
            o.w = tanhf(acc[r].w + sb[4 * cg + 3]);
            *(float4*)(hout + (size_t)row * D_OUT + 4 * cg) = o;
        }
    }
}

// ---------------------------------------------------------------------------
// Head: out = h @ Wlin + blin   ([n,64] x [64,10])
// ---------------------------------------------------------------------------
__global__ __launch_bounds__(THREADS)
void head_kernel(const float* __restrict__ h, const float* __restrict__ W,
                 const float* __restrict__ bias, float* __restrict__ out, int n) {
    __shared__ float sW[64 * 10];
    __shared__ float sb[10];
    for (int i = threadIdx.x; i < 640; i += THREADS) sW[i] = W[i];
    if (threadIdx.x < 10) sb[threadIdx.x] = bias[threadIdx.x];
    __syncthreads();
    int idx = blockIdx.x * THREADS + threadIdx.x;
    if (idx >= n * 10) return;
    int row = idx / 10;
    int col = idx - row * 10;
    const float* __restrict__ hr = h + (size_t)row * 64;
    float acc = sb[col];
#pragma unroll 16
    for (int k = 0; k < 64; ++k) acc += hr[k] * sW[k * 10 + col];
    out[idx] = acc;
}

extern "C" void kernel_launch(void* const* d_in, const int* in_sizes, int n_in,
                              void* d_out, int out_size, void* d_ws, size_t ws_size,
                              hipStream_t stream) {
    const float* x    = (const float*)d_in[0];
    const void*  ei   = d_in[1];
    const float* W1l  = (const float*)d_in[2];
    const float* W1r  = (const float*)d_in[3];
    const float* b1   = (const float*)d_in[4];
    const float* W2l  = (const float*)d_in[5];
    const float* W2r  = (const float*)d_in[6];
    const float* b2   = (const float*)d_in[7];
    const float* W3l  = (const float*)d_in[8];
    const float* W3r  = (const float*)d_in[9];
    const float* b3   = (const float*)d_in[10];
    const float* Wlin = (const float*)d_in[11];
    const float* blin = (const float*)d_in[12];
    float* out = (float*)d_out;

    const int n = in_sizes[0] / 128;   // 100000
    const int E = in_sizes[1] / 2;     // 1600000

    // --- workspace carve-up (~135 MB) ---
    char* ws = (char*)d_ws;
    size_t off = 0;
    auto carve = [&](size_t bytes) {
        void* p = ws + off;
        off += (bytes + 255) & ~(size_t)255;
        return p;
    };
    int*   flag   = (int*)  carve(256);
    int*   cnt    = (int*)  carve((size_t)n * 4);
    int*   rowptr = (int*)  carve((size_t)(n + 1) * 4);
    int*   wptr   = (int*)  carve((size_t)n * 4);
    int*   bsum   = (int*)  carve(4096);
    int*   esrc   = (int*)  carve((size_t)E * 4);
    float* p      = (float*)carve((size_t)n * 64 * 4);  // also reused as agg
    float* q      = (float*)carve((size_t)n * 64 * 4);
    float* h1     = (float*)carve((size_t)n * 64 * 4);
    float* h2     = (float*)carve((size_t)n * 128 * 4);
    float* h3     = h1;   // h1 dead after layer 2
    (void)ws_size;

    const int eblocks = (E + THREADS - 1) / THREADS;
    const int nscan   = (n + 1023) / 1024;

    // --- CSR build (once; graph shared by all layers) ---
    detect_kernel<<<1, 64, 0, stream>>>((const unsigned*)ei, flag);
    hipMemsetAsync(cnt, 0, (size_t)n * 4, stream);
    count_kernel<<<eblocks, THREADS, 0, stream>>>(ei, flag, cnt, E);
    scan_partial_kernel<<<nscan, 256, 0, stream>>>(cnt, bsum, n);
    scan_bsum_kernel<<<1, 64, 0, stream>>>(bsum, rowptr + n, nscan);
    scan_final_kernel<<<nscan, 256, 0, stream>>>(cnt, bsum, rowptr, wptr, n);
    place_kernel<<<eblocks, THREADS, 0, stream>>>(ei, flag, wptr, esrc, E);

    // --- layer 1: project-then-aggregate (mean(x)@W = mean(x@W)) ---
    dual_gemm_kernel<128, 64, 2><<<(n + 63) / 64, 512, 0, stream>>>(
        x, W1l, W1r, p, q, n);
    gather_fuse_kernel<<<(n + 15) / 16, THREADS, 0, stream>>>(
        rowptr, esrc, p, q, b1, h1, n);

    // --- layer 2: aggregate-then-project (64 -> 128) ---
    gather_mean_kernel<<<(n + 15) / 16, THREADS, 0, stream>>>(
        rowptr, esrc, h1, p /*agg*/, n);
    layer_kernel<64, 128, 2><<<(n + 31) / 32, 512, 0, stream>>>(
        p /*agg*/, h1, W2l, W2r, b2, h2, n);

    // --- layer 3: project-then-aggregate ---
    dual_gemm_kernel<128, 64, 2><<<(n + 63) / 64, 512, 0, stream>>>(
        h2, W3l, W3r, p, q, n);
    gather_fuse_kernel<<<(n + 15) / 16, THREADS, 0, stream>>>(
        rowptr, esrc, p, q, b3, h3, n);

    // --- head ---
    head_kernel<<<(n * 10 + THREADS - 1) / THREADS, THREADS, 0, stream>>>(
        h3, Wlin, blin, out, n);
}